// Round 5
// baseline (476.435 us; speedup 1.0000x reference)
//
#include <hip/hip_runtime.h>

// N=65536, E=1048576, nfeat=64, nhid=128. Inputs fp32; edge_index int32.
// 3-kernel pipeline:
//  K1: edge binning (512 buckets x 128 nodes) + x->bf16 + W1->bf16 + sigmas
//  K2: streaming edge scatter into fp32 LDS accumulator (ds_add_f32) --
//      NO CSR build, no per-node reduction loops -- then MFMA gemm1
//      (+BN atomics); h1 tile (bf16) stored in d_out's own 64KB tile slot.
//  K3: per-block BN fold of W2 (exact fp32 accb) + MFMA gemm2, in-place on d_out.
// History: r2 wide-gather regressed 2x (chain count); r4 TLP-doubling only -3us
// (per-iteration lgkm->vmem->drain structure was the bound, not wave count).
// This round deletes the reduction structure: edge-parallel LDS-atomic scatter.

#define BN_EPS 1e-5f
#define NB   512      // buckets (128 nodes each)
#define CAP  2816     // per-bucket capacity (avg 2048, +17 sigma; mult of 4)

typedef float f4 __attribute__((ext_vector_type(4)));
typedef short bf8 __attribute__((ext_vector_type(8)));   // 8 bf16 = 4 VGPRs

__device__ inline short f2bf(float f) {
    unsigned u = __float_as_uint(f);
    u = u + 0x7fffu + ((u >> 16) & 1u);   // round-to-nearest-even
    return (short)(u >> 16);
}
__device__ inline float bf2f(unsigned short u) {
    return __uint_as_float((unsigned)u << 16);
}
__device__ inline unsigned pk2(float a, float b) {
    return (unsigned)(unsigned short)f2bf(a) |
           ((unsigned)(unsigned short)f2bf(b) << 16);
}

// ================= K1: binning + casts + sigma =================
// blocks 0..255: bin 4096 edges each. Packed: [31:23]=bucket [22:7]=src [6:0]=dst&127
// blocks 256..511: x->bf16 (each thread 4 uint4)
// block 512: W1->bf16 + spectral-norm sigmas
__global__ __launch_bounds__(512) void k1_bin(const int* __restrict__ ei, int E,
                                              int* __restrict__ gcount,
                                              unsigned* __restrict__ pairs,
                                              const float* __restrict__ x,
                                              unsigned* __restrict__ xbf2,
                                              const float* __restrict__ W1,
                                              short* __restrict__ w1bf,
                                              const float* __restrict__ u1,
                                              const float* __restrict__ W2,
                                              const float* __restrict__ u2,
                                              float* __restrict__ sinv) {
    __shared__ int hist[512];
    __shared__ int sbase[512];
    __shared__ int cur[512];
    __shared__ int gofs[512];
    __shared__ unsigned stage[4096];
    int t = threadIdx.x;
    int bid = blockIdx.x;

    if (bid < 256) {
        hist[t] = 0;
        __syncthreads();

        const uint4* s4 = (const uint4*)ei + bid * 1024;
        const uint4* d4 = (const uint4*)(ei + E) + bid * 1024;
        unsigned pk[8];
#pragma unroll
        for (int i = 0; i < 2; i++) {
            int idx = i * 512 + t;
            uint4 sv = s4[idx];
            uint4 dv = d4[idx];
            pk[i * 4 + 0] = ((dv.x >> 7) << 23) | (sv.x << 7) | (dv.x & 127u);
            pk[i * 4 + 1] = ((dv.y >> 7) << 23) | (sv.y << 7) | (dv.y & 127u);
            pk[i * 4 + 2] = ((dv.z >> 7) << 23) | (sv.z << 7) | (dv.z & 127u);
            pk[i * 4 + 3] = ((dv.w >> 7) << 23) | (sv.w << 7) | (dv.w & 127u);
            atomicAdd(&hist[dv.x >> 7], 1);
            atomicAdd(&hist[dv.y >> 7], 1);
            atomicAdd(&hist[dv.z >> 7], 1);
            atomicAdd(&hist[dv.w >> 7], 1);
        }
        __syncthreads();

        // single-wave inclusive scan of hist[512] (8 elems/lane, wave 0)
        if (t < 64) {
            int e[8]; int s = 0;
#pragma unroll
            for (int k = 0; k < 8; k++) { e[k] = hist[8 * t + k]; s += e[k]; }
#pragma unroll
            for (int o = 1; o < 64; o <<= 1) {
                int v = __shfl_up(s, o);
                if (t >= o) s += v;
            }
            int run = s;   // inclusive sum through lane's last element
#pragma unroll
            for (int k = 7; k >= 0; k--) {
                hist[8 * t + k] = run;     // inclusive at 8t+k
                run -= e[k];
                sbase[8 * t + k] = run;    // exclusive at 8t+k
                cur[8 * t + k] = run;
            }
        }
        __syncthreads();

#pragma unroll
        for (int i = 0; i < 8; i++) {
            int p = atomicAdd(&cur[pk[i] >> 23], 1);
            stage[p] = pk[i];
        }
        __syncthreads();

        int cntb = hist[t] - sbase[t];
        gofs[t] = atomicAdd(&gcount[t], cntb);
        __syncthreads();

#pragma unroll
        for (int i = 0; i < 8; i++) {
            int p = i * 512 + t;
            unsigned v = stage[p];
            int b = (int)(v >> 23);
            int li = p - sbase[b];
            pairs[(size_t)b * CAP + gofs[b] + li] = v & 0x7FFFFFu;
        }
    } else if (bid < 512) {
        // x cast: 256 blocks x 512 thr x 4 uint4 = 524288 uint4 = N*8
        int cb = bid - 256;
        const float4* xp = (const float4*)x;
#pragma unroll
        for (int k = 0; k < 4; k++) {
            int i = cb * 2048 + k * 512 + t;
            float4 a = xp[2 * i], b = xp[2 * i + 1];
            uint4 o = {pk2(a.x, a.y), pk2(a.z, a.w), pk2(b.x, b.y), pk2(b.z, b.w)};
            ((uint4*)xbf2)[i] = o;
        }
    } else {
        // W1 cast: 8192 elems
#pragma unroll
        for (int k = 0; k < 2; k++) {
            int idx = k * 512 + t;           // uint4 index (1024 total)
            const float4* wp = (const float4*)W1;
            float4 a = wp[2 * idx], b = wp[2 * idx + 1];
            uint4 o = {pk2(a.x, a.y), pk2(a.z, a.w), pk2(b.x, b.y), pk2(b.z, b.w)};
            ((uint4*)w1bf)[idx] = o;
        }
        // ---- sigmas (LDS-tree, no shuffle chains) ----
        float* red = (float*)stage;     // 512 floats
        float* v   = (float*)hist;      // 128 floats
        float* sq  = (float*)sbase;     // 512 floats scratch

        // === W1 (128x64) ===
        {
            int j = t & 63, q = t >> 6;
            float s = 0.f;
            for (int i = q * 16; i < q * 16 + 16; i++) s += W1[i * 64 + j] * u1[i];
            red[t] = s;
        }
        __syncthreads();
        if (t < 64) {
            float vj = 0.f;
#pragma unroll
            for (int g = 0; g < 8; g++) vj += red[g * 64 + t];
            v[t] = vj; sq[t] = vj * vj;
        }
        __syncthreads();
        for (int s2 = 32; s2 > 0; s2 >>= 1) {
            if (t < s2) sq[t] += sq[t + s2];
            __syncthreads();
        }
        if (t < 64) v[t] = v[t] / (sqrtf(sq[0]) + 1e-12f);
        __syncthreads();
        {
            int r = t >> 2, h = t & 3;
            const float4* wr = (const float4*)(W1 + r * 64 + h * 16);
            const float4* vv = (const float4*)v + h * 4;
            float s = 0.f;
#pragma unroll
            for (int k = 0; k < 4; k++) {
                float4 a = wr[k]; float4 b = vv[k];
                s += a.x * b.x + a.y * b.y + a.z * b.z + a.w * b.w;
            }
            red[t] = s;
        }
        __syncthreads();
        if (t < 128) {
            float tr = (red[4 * t] + red[4 * t + 1]) + (red[4 * t + 2] + red[4 * t + 3]);
            sq[t] = tr * tr;
        }
        __syncthreads();
        for (int s2 = 64; s2 > 0; s2 >>= 1) {
            if (t < s2) sq[t] += sq[t + s2];
            __syncthreads();
        }
        if (t == 0) { float nt2 = sq[0]; sinv[0] = (sqrtf(nt2) + 1e-12f) / nt2; }
        __syncthreads();

        // === W2 (128x128) ===
        {
            int j = t & 127, q = t >> 7;
            float s = 0.f;
            for (int i = q * 32; i < q * 32 + 32; i++) s += W2[i * 128 + j] * u2[i];
            red[t] = s;
        }
        __syncthreads();
        if (t < 128) {
            float vj = (red[t] + red[128 + t]) + (red[256 + t] + red[384 + t]);
            v[t] = vj; sq[t] = vj * vj;
        }
        __syncthreads();
        for (int s2 = 64; s2 > 0; s2 >>= 1) {
            if (t < s2) sq[t] += sq[t + s2];
            __syncthreads();
        }
        if (t < 128) v[t] = v[t] / (sqrtf(sq[0]) + 1e-12f);
        __syncthreads();
        {
            int r = t >> 2, h = t & 3;
            const float4* wr = (const float4*)(W2 + r * 128 + h * 32);
            const float4* vv = (const float4*)v + h * 8;
            float s = 0.f;
#pragma unroll
            for (int k = 0; k < 8; k++) {
                float4 a = wr[k]; float4 b = vv[k];
                s += a.x * b.x + a.y * b.y + a.z * b.z + a.w * b.w;
            }
            red[t] = s;
        }
        __syncthreads();
        if (t < 128) {
            float tr = (red[4 * t] + red[4 * t + 1]) + (red[4 * t + 2] + red[4 * t + 3]);
            sq[t] = tr * tr;
        }
        __syncthreads();
        for (int s2 = 64; s2 > 0; s2 >>= 1) {
            if (t < s2) sq[t] += sq[t + s2];
            __syncthreads();
        }
        if (t == 0) { float nt2 = sq[0]; sinv[1] = (sqrtf(nt2) + 1e-12f) / nt2; }
    }
}

// ================= K2: aggregate + gemm1 fused =================
// One 1024-thread block (16 waves) per bucket of 128 nodes.
// Phase 1: streaming edge scatter -- each wave-instr covers 2 edges (32
// lanes/edge, 4B/lane gather, coalesced 128B/edge); converted values are
// atomically added (ds_add_f32) into the fp32 h-accumulator hf[128][64]
// (chunk-XOR swizzled so the MFMA A-read stays conflict-cheap). Fire-and-
// forget: no CSR, no per-node loops, no vmcnt(0) drains.
// Phase 2: self-row plain adds. Phase 3: MFMA (waves 0-7, A-frag read as
// 2x float4 + pack to bf16), relu/scale epilogue, BN sums, h1 store.
__global__ __launch_bounds__(1024, 8) void k2_agg_gemm1(
        const unsigned* __restrict__ pairs,
        const int* __restrict__ gcount,
        const unsigned* __restrict__ xbf2,
        const short* __restrict__ w1bf,
        const float* __restrict__ b1,
        const float* __restrict__ sinv,
        char* __restrict__ outbase,          // d_out as bytes
        float* __restrict__ bnacc) {
    __shared__ float hf[8192];              // 32 KB fp32 h accum; later h1 bf16 tile
    __shared__ short w1s[8192];             // 16 KB W1 tile (bf16, swizzled)
    __shared__ float red1[1024], red2[1024];// 8 KB
    int t = threadIdx.x;
    int b = blockIdx.x;
    int cnt = gcount[b];

    // ---- zero hf + stage W1 (both done before first barrier) ----
    {
        float4* z4 = (float4*)hf;
#pragma unroll
        for (int i = 0; i < 2; i++) z4[i * 1024 + t] = (float4){0.f, 0.f, 0.f, 0.f};
    }
    {
        const bf8* wsrc = (const bf8*)w1bf;
        int row = t >> 3, c = t & 7;
        int cs = c ^ (row & 7);
        *(bf8*)&w1s[row * 64 + cs * 8] = wsrc[t];
    }
    __syncthreads();

    int w = t >> 6;
    int lane = t & 63;
    int hl = lane >> 5;        // which edge of the pair (0/1)
    int l = lane & 31;         // feature pair index (feats 2l, 2l+1)
    const unsigned* pg = pairs + (size_t)b * CAP;

    // ---- streaming edge scatter (unroll-4 pair groups per wave) ----
    int npairs = (cnt + 1) >> 1;
    for (int jp = w * 4; jp < npairs; jp += 64) {
#pragma unroll
        for (int k = 0; k < 4; k++) {
            int e = 2 * (jp + k) + hl;
            bool p = e < cnt;
            unsigned pv = pg[p ? e : 0];     // broadcast read (2 addrs/wave)
            int src = (int)(pv >> 7);
            int d = (int)(pv & 127u);
            unsigned xv = xbf2[(size_t)src * 32 + l];
            float f0 = p ? bf2f((unsigned short)xv) : 0.f;
            float f1 = p ? bf2f((unsigned short)(xv >> 16)) : 0.f;
            int base = d * 64 + (((l >> 2) ^ (d & 7)) << 3) + 2 * (l & 3);
            atomicAdd(&hf[base], f0);
            atomicAdd(&hf[base + 1], f1);
        }
    }
    __syncthreads();

    // ---- self-row: plain adds, disjoint ownership (4096 uints, 4/thread) ----
#pragma unroll
    for (int i = 0; i < 4; i++) {
        int idx = i * 1024 + t;              // 0..4095
        int n = idx >> 5, ll = idx & 31;
        unsigned xv = xbf2[(size_t)(b * 128 + n) * 32 + ll];
        int base = n * 64 + (((ll >> 2) ^ (n & 7)) << 3) + 2 * (ll & 3);
        hf[base]     += bf2f((unsigned short)xv);
        hf[base + 1] += bf2f((unsigned short)(xv >> 16));
    }
    __syncthreads();

    // ---- MFMA: waves 0-7 (t<512), wave w handles nodes w*16..+15 ----
    int l15 = lane & 15, quad = lane >> 4;
    float s1 = sinv[0];
    f4 acc[8];
#pragma unroll
    for (int nt = 0; nt < 8; nt++) acc[nt] = (f4){0.f, 0.f, 0.f, 0.f};

    if (t < 512) {
#pragma unroll
        for (int ks = 0; ks < 2; ks++) {
            bf8 a, bfr[8];
            {
                int node = w * 16 + l15;
                int cs = (ks * 4 + quad) ^ (node & 7);
                const float4* ap = (const float4*)&hf[node * 64 + cs * 8];
                float4 a0 = ap[0], a1 = ap[1];
                a[0] = f2bf(a0.x); a[1] = f2bf(a0.y);
                a[2] = f2bf(a0.z); a[3] = f2bf(a0.w);
                a[4] = f2bf(a1.x); a[5] = f2bf(a1.y);
                a[6] = f2bf(a1.z); a[7] = f2bf(a1.w);
            }
#pragma unroll
            for (int nt = 0; nt < 8; nt++) {
                int o = nt * 16 + l15;
                int cs = (ks * 4 + quad) ^ (o & 7);
                bfr[nt] = *(const bf8*)&w1s[o * 64 + cs * 8];
            }
#pragma unroll
            for (int nt = 0; nt < 8; nt++)
                acc[nt] = __builtin_amdgcn_mfma_f32_16x16x32_bf16(a, bfr[nt], acc[nt], 0, 0, 0);
        }

        // ---- epilogue: relu(s1*acc+b1), BN col sums ----
#pragma unroll
        for (int nt = 0; nt < 8; nt++) {
            float bb = b1[nt * 16 + l15];
            float s = 0.f, q = 0.f;
#pragma unroll
            for (int r = 0; r < 4; r++) {
                float v = fmaxf(fmaf(acc[nt][r], s1, bb), 0.f);
                acc[nt][r] = v;
                s += v; q += v * v;
            }
            s += __shfl_xor(s, 16); s += __shfl_xor(s, 32);
            q += __shfl_xor(q, 16); q += __shfl_xor(q, 32);
            if (quad == 0) {
                red1[w * 128 + nt * 16 + l15] = s;
                red2[w * 128 + nt * 16 + l15] = q;
            }
        }
    }
    __syncthreads();   // hf fragments consumed; overlay h1 tile (128x128 bf16)

    short* u16 = (short*)hf;
    if (t < 512) {
#pragma unroll
        for (int nt = 0; nt < 8; nt++) {
            int col = nt * 16 + l15;
#pragma unroll
            for (int r = 0; r < 4; r++) {
                int row = w * 16 + quad * 4 + r;
                int cs = (col >> 3) ^ (row & 15);
                u16[row * 128 + cs * 8 + (col & 7)] = f2bf(acc[nt][r]);
            }
        }
    }
    __syncthreads();

    // ---- h1 tile -> d_out slot b (first 32 KB of its 64 KB region) ----
    bf8* dst = (bf8*)(outbase + (size_t)b * 65536);
#pragma unroll
    for (int i = 0; i < 2; i++) {
        int idx = i * 1024 + t;             // 2048 bf8
        int row = idx >> 4, c = idx & 15;
        int cs = c ^ (row & 15);
        dst[idx] = *(const bf8*)&u16[row * 128 + cs * 8];
    }
    // BN atomics
    if (t < 128) {
        float s = 0.f, q = 0.f;
#pragma unroll
        for (int g = 0; g < 8; g++) { s += red1[g * 128 + t]; q += red2[g * 128 + t]; }
        atomicAdd(&bnacc[t], s);
        atomicAdd(&bnacc[128 + t], q);
    }
}

// ================= K3: BN fold + gemm2 fused =================
// 512 blocks x 256 threads. Each block: fold W2 (redundant, cheap) into LDS
// bf16, stage its h1 tile from d_out slot, MFMA, overwrite slot with fp32 out.
__global__ __launch_bounds__(256) void k3_fold_gemm2(
        const float* __restrict__ bnacc, int N,
        const float* __restrict__ gamma,
        const float* __restrict__ beta,
        const float* __restrict__ W2,
        const float* __restrict__ b2,
        const float* __restrict__ sinv,
        char* __restrict__ outbase) {
    __shared__ short s5[32768];   // [0..16383]=h1 tile, [16384..]=w2s; 64 KB
    float* fs = (float*)s5;       // transient: a_s[0..127], c_s[128..255], b2f[256..383]
    int t = threadIdx.x;
    int b = blockIdx.x;

    if (t < 128) {
        float mean = bnacc[t] / (float)N;
        float var = bnacc[t + 128] / (float)N - mean * mean;
        float rstd = rsqrtf(var + BN_EPS);
        float a = rstd * gamma[t];
        fs[t] = a;
        fs[128 + t] = beta[t] - mean * a;
    }
    __syncthreads();

    // stage folded W2 (bf16, 16-chunk swizzle): thread -> row o=t>>1, 64 cols
    float s2 = sinv[1];
    {
        int o = t >> 1;
        int jbase = (t & 1) * 64;
        const float4* wr = (const float4*)(W2 + o * 128 + jbase);
#pragma unroll
        for (int k = 0; k < 8; k++) {
            int c = (jbase >> 3) + k;
            float4 a = wr[2 * k], bb = wr[2 * k + 1];
            int j0 = jbase + k * 8;
            bf8 v;
            v[0] = f2bf(a.x * s2 * fs[j0 + 0]);
            v[1] = f2bf(a.y * s2 * fs[j0 + 1]);
            v[2] = f2bf(a.z * s2 * fs[j0 + 2]);
            v[3] = f2bf(a.w * s2 * fs[j0 + 3]);
            v[4] = f2bf(bb.x * s2 * fs[j0 + 4]);
            v[5] = f2bf(bb.y * s2 * fs[j0 + 5]);
            v[6] = f2bf(bb.z * s2 * fs[j0 + 6]);
            v[7] = f2bf(bb.w * s2 * fs[j0 + 7]);
            int cs = c ^ (o & 15);
            *(bf8*)&s5[16384 + o * 128 + cs * 8] = v;
        }
    }
    // exact fp32 b2f (vectorized: 32 float4 loads, unrolled, s2 folded once)
    if (t < 128) {
        const float4* wr = (const float4*)(W2 + t * 128);
        float accb = 0.f;
#pragma unroll
        for (int k = 0; k < 32; k++) {
            float4 a = wr[k];
            accb += a.x * fs[128 + 4 * k + 0] + a.y * fs[128 + 4 * k + 1] +
                    a.z * fs[128 + 4 * k + 2] + a.w * fs[128 + 4 * k + 3];
        }
        fs[256 + t] = b2[t] + accb * s2;
    }
    __syncthreads();

    int w = t >> 6;
    int lane = t & 63;
    int l15 = lane & 15, quad = lane >> 4;
    float b2v[8];
#pragma unroll
    for (int nt = 0; nt < 8; nt++) b2v[nt] = fs[256 + nt * 16 + l15];
    __syncthreads();   // b2v read; fs region free for h1 tile

    // stage h1 tile from d_out slot b
    {
        const bf8* hsrc = (const bf8*)(outbase + (size_t)b * 65536);
#pragma unroll
        for (int i = 0; i < 8; i++) {
            int idx = i * 256 + t;          // 2048 bf8
            int row = idx >> 4, c = idx & 15;
            int cs = c ^ (row & 15);
            *(bf8*)&s5[row * 128 + cs * 8] = hsrc[idx];
        }
    }
    __syncthreads();

    f4 acc[2][8];
#pragma unroll
    for (int mt = 0; mt < 2; mt++)
#pragma unroll
        for (int nt = 0; nt < 8; nt++) acc[mt][nt] = (f4){0.f, 0.f, 0.f, 0.f};

#pragma unroll
    for (int ks = 0; ks < 4; ks++) {
        bf8 a[2], bfr[8];
#pragma unroll
        for (int mt = 0; mt < 2; mt++) {
            int node = w * 32 + mt * 16 + l15;
            int cs = (ks * 4 + quad) ^ (node & 15);
            a[mt] = *(const bf8*)&s5[node * 128 + cs * 8];
        }
#pragma unroll
        for (int nt = 0; nt < 8; nt++) {
            int o = nt * 16 + l15;
            int cs = (ks * 4 + quad) ^ (o & 15);
            bfr[nt] = *(const bf8*)&s5[16384 + o * 128 + cs * 8];
        }
#pragma unroll
        for (int mt = 0; mt < 2; mt++)
#pragma unroll
            for (int nt = 0; nt < 8; nt++)
                acc[mt][nt] = __builtin_amdgcn_mfma_f32_16x16x32_bf16(
                    a[mt], bfr[nt], acc[mt][nt], 0, 0, 0);
    }

    float* out = (float*)(outbase + (size_t)b * 65536);
#pragma unroll
    for (int mt = 0; mt < 2; mt++)
#pragma unroll
        for (int nt = 0; nt < 8; nt++)
#pragma unroll
            for (int r = 0; r < 4; r++) {
                int row = w * 32 + mt * 16 + quad * 4 + r;   // local node
                out[(size_t)row * 128 + nt * 16 + l15] = acc[mt][nt][r] + b2v[nt];
            }
}

extern "C" void kernel_launch(void* const* d_in, const int* in_sizes, int n_in,
                              void* d_out, int out_size, void* d_ws, size_t ws_size,
                              hipStream_t stream) {
    const float* x     = (const float*)d_in[0];
    const int*   ei    = (const int*)d_in[1];
    const float* W1    = (const float*)d_in[2];
    const float* b1    = (const float*)d_in[3];
    const float* u1    = (const float*)d_in[4];
    const float* gamma = (const float*)d_in[5];
    const float* beta  = (const float*)d_in[6];
    const float* W2    = (const float*)d_in[7];
    const float* b2    = (const float*)d_in[8];
    const float* u2    = (const float*)d_in[9];

    int N = in_sizes[0] / 64;     // 65536
    int E = in_sizes[1] / 2;      // 1048576

    char* ws = (char*)d_ws;
    size_t off = 0;
    unsigned* pairs = (unsigned*)(ws + off); off += (size_t)NB * CAP * 4;  // 5.77 MB
    unsigned short* xbf = (unsigned short*)(ws + off); off += (size_t)N * 64 * 2; // 8 MB
    int*   gcount  = (int*)(ws + off);   off += 512 * 4;
    float* bnacc   = (float*)(ws + off); off += 256 * 4;   // contiguous w/ gcount
    float* sinv    = (float*)(ws + off); off += 16 * 4;
    short* w1bf    = (short*)(ws + off); off += 128 * 64 * 2;

    // zero gcount(512 int) + bnacc(256 float) in one memset (contiguous)
    hipMemsetAsync(gcount, 0, 512 * 4 + 256 * 4, stream);
    // K1: binning + x/W1 casts + sigmas
    k1_bin<<<513, 512, 0, stream>>>(ei, E, gcount, pairs, x, (unsigned*)xbf,
                                    W1, w1bf, u1, W2, u2, sinv);
    // K2: edge-scatter aggregate + gemm1 -> h1 tiles + BN atomics
    k2_agg_gemm1<<<NB, 1024, 0, stream>>>(pairs, gcount, (const unsigned*)xbf,
                                          w1bf, b1, sinv, (char*)d_out, bnacc);
    // K3: BN fold + gemm2, in place on d_out
    k3_fold_gemm2<<<NB, 256, 0, stream>>>(bnacc, N, gamma, beta, W2, b2, sinv,
                                          (char*)d_out);
}

// Round 6
// 152.966 us; speedup vs baseline: 3.1146x; 3.1146x over previous
//
#include <hip/hip_runtime.h>

// N=65536, E=1048576, nfeat=64, nhid=128. Inputs fp32; edge_index int32.
// 3-kernel pipeline:
//  K1: edge binning (512 buckets x 128 nodes) + x->bf16 + W1->bf16 + sigmas
//  K2: per-bucket LDS-CSR + 2-node-interleaved register gather (predicated
//      tails, direct LDS h-row writes) + MFMA gemm1 (+BN atomics);
//      h1 tile (bf16) stored in d_out's own 64KB tile slot (first 32KB).
//      1024-thr blocks (16 waves, 8 nodes/wave in gather) for 32 waves/CU;
//      MFMA/epilogue stays on waves 0-7 (t<512) with the proven mapping.
//  K3: per-block BN fold of W2 (exact fp32 accb) + MFMA gemm2, in-place on d_out.
// History (measured): r1 interleave+pred-tails 155.7; r2 wide 16B/lane gather
// 162.8 (fewer chains = 2x k2 regression); r4 = THIS structure, 154.3 (best);
// r5 LDS-atomic edge scatter 476 (atomic pipe serialized, all units idle).
// The narrow 8-chain per-node gather is the empirically dominant structure.

#define BN_EPS 1e-5f
#define NB   512      // buckets (128 nodes each)
#define CAP  2816     // per-bucket capacity (avg 2048, +17 sigma; mult of 4)

typedef float f4 __attribute__((ext_vector_type(4)));
typedef short bf8 __attribute__((ext_vector_type(8)));   // 8 bf16 = 4 VGPRs

__device__ inline short f2bf(float f) {
    unsigned u = __float_as_uint(f);
    u = u + 0x7fffu + ((u >> 16) & 1u);   // round-to-nearest-even
    return (short)(u >> 16);
}
__device__ inline float bf2f(unsigned short u) {
    return __uint_as_float((unsigned)u << 16);
}
__device__ inline unsigned pk2(float a, float b) {
    return (unsigned)(unsigned short)f2bf(a) |
           ((unsigned)(unsigned short)f2bf(b) << 16);
}

// ================= K1: binning + casts + sigma =================
// blocks 0..255: bin 4096 edges each. Packed: [31:23]=bucket [22:7]=src [6:0]=dst&127
// blocks 256..511: x->bf16 (each thread 4 uint4)
// block 512: W1->bf16 + spectral-norm sigmas
__global__ __launch_bounds__(512) void k1_bin(const int* __restrict__ ei, int E,
                                              int* __restrict__ gcount,
                                              unsigned* __restrict__ pairs,
                                              const float* __restrict__ x,
                                              unsigned* __restrict__ xbf2,
                                              const float* __restrict__ W1,
                                              short* __restrict__ w1bf,
                                              const float* __restrict__ u1,
                                              const float* __restrict__ W2,
                                              const float* __restrict__ u2,
                                              float* __restrict__ sinv) {
    __shared__ int hist[512];
    __shared__ int sbase[512];
    __shared__ int cur[512];
    __shared__ int gofs[512];
    __shared__ unsigned stage[4096];
    int t = threadIdx.x;
    int bid = blockIdx.x;

    if (bid < 256) {
        hist[t] = 0;
        __syncthreads();

        const uint4* s4 = (const uint4*)ei + bid * 1024;
        const uint4* d4 = (const uint4*)(ei + E) + bid * 1024;
        unsigned pk[8];
#pragma unroll
        for (int i = 0; i < 2; i++) {
            int idx = i * 512 + t;
            uint4 sv = s4[idx];
            uint4 dv = d4[idx];
            pk[i * 4 + 0] = ((dv.x >> 7) << 23) | (sv.x << 7) | (dv.x & 127u);
            pk[i * 4 + 1] = ((dv.y >> 7) << 23) | (sv.y << 7) | (dv.y & 127u);
            pk[i * 4 + 2] = ((dv.z >> 7) << 23) | (sv.z << 7) | (dv.z & 127u);
            pk[i * 4 + 3] = ((dv.w >> 7) << 23) | (sv.w << 7) | (dv.w & 127u);
            atomicAdd(&hist[dv.x >> 7], 1);
            atomicAdd(&hist[dv.y >> 7], 1);
            atomicAdd(&hist[dv.z >> 7], 1);
            atomicAdd(&hist[dv.w >> 7], 1);
        }
        __syncthreads();

        // single-wave inclusive scan of hist[512] (8 elems/lane, wave 0)
        if (t < 64) {
            int e[8]; int s = 0;
#pragma unroll
            for (int k = 0; k < 8; k++) { e[k] = hist[8 * t + k]; s += e[k]; }
#pragma unroll
            for (int o = 1; o < 64; o <<= 1) {
                int v = __shfl_up(s, o);
                if (t >= o) s += v;
            }
            int run = s;   // inclusive sum through lane's last element
#pragma unroll
            for (int k = 7; k >= 0; k--) {
                hist[8 * t + k] = run;     // inclusive at 8t+k
                run -= e[k];
                sbase[8 * t + k] = run;    // exclusive at 8t+k
                cur[8 * t + k] = run;
            }
        }
        __syncthreads();

#pragma unroll
        for (int i = 0; i < 8; i++) {
            int p = atomicAdd(&cur[pk[i] >> 23], 1);
            stage[p] = pk[i];
        }
        __syncthreads();

        int cntb = hist[t] - sbase[t];
        gofs[t] = atomicAdd(&gcount[t], cntb);
        __syncthreads();

#pragma unroll
        for (int i = 0; i < 8; i++) {
            int p = i * 512 + t;
            unsigned v = stage[p];
            int b = (int)(v >> 23);
            int li = p - sbase[b];
            pairs[(size_t)b * CAP + gofs[b] + li] = v & 0x7FFFFFu;
        }
    } else if (bid < 512) {
        // x cast: 256 blocks x 512 thr x 4 uint4 = 524288 uint4 = N*8
        int cb = bid - 256;
        const float4* xp = (const float4*)x;
#pragma unroll
        for (int k = 0; k < 4; k++) {
            int i = cb * 2048 + k * 512 + t;
            float4 a = xp[2 * i], b = xp[2 * i + 1];
            uint4 o = {pk2(a.x, a.y), pk2(a.z, a.w), pk2(b.x, b.y), pk2(b.z, b.w)};
            ((uint4*)xbf2)[i] = o;
        }
    } else {
        // W1 cast: 8192 elems
#pragma unroll
        for (int k = 0; k < 2; k++) {
            int idx = k * 512 + t;           // uint4 index (1024 total)
            const float4* wp = (const float4*)W1;
            float4 a = wp[2 * idx], b = wp[2 * idx + 1];
            uint4 o = {pk2(a.x, a.y), pk2(a.z, a.w), pk2(b.x, b.y), pk2(b.z, b.w)};
            ((uint4*)w1bf)[idx] = o;
        }
        // ---- sigmas (LDS-tree, no shuffle chains) ----
        float* red = (float*)stage;     // 512 floats
        float* v   = (float*)hist;      // 128 floats
        float* sq  = (float*)sbase;     // 512 floats scratch

        // === W1 (128x64) ===
        {
            int j = t & 63, q = t >> 6;
            float s = 0.f;
            for (int i = q * 16; i < q * 16 + 16; i++) s += W1[i * 64 + j] * u1[i];
            red[t] = s;
        }
        __syncthreads();
        if (t < 64) {
            float vj = 0.f;
#pragma unroll
            for (int g = 0; g < 8; g++) vj += red[g * 64 + t];
            v[t] = vj; sq[t] = vj * vj;
        }
        __syncthreads();
        for (int s2 = 32; s2 > 0; s2 >>= 1) {
            if (t < s2) sq[t] += sq[t + s2];
            __syncthreads();
        }
        if (t < 64) v[t] = v[t] / (sqrtf(sq[0]) + 1e-12f);
        __syncthreads();
        {
            int r = t >> 2, h = t & 3;
            const float4* wr = (const float4*)(W1 + r * 64 + h * 16);
            const float4* vv = (const float4*)v + h * 4;
            float s = 0.f;
#pragma unroll
            for (int k = 0; k < 4; k++) {
                float4 a = wr[k]; float4 b = vv[k];
                s += a.x * b.x + a.y * b.y + a.z * b.z + a.w * b.w;
            }
            red[t] = s;
        }
        __syncthreads();
        if (t < 128) {
            float tr = (red[4 * t] + red[4 * t + 1]) + (red[4 * t + 2] + red[4 * t + 3]);
            sq[t] = tr * tr;
        }
        __syncthreads();
        for (int s2 = 64; s2 > 0; s2 >>= 1) {
            if (t < s2) sq[t] += sq[t + s2];
            __syncthreads();
        }
        if (t == 0) { float nt2 = sq[0]; sinv[0] = (sqrtf(nt2) + 1e-12f) / nt2; }
        __syncthreads();

        // === W2 (128x128) ===
        {
            int j = t & 127, q = t >> 7;
            float s = 0.f;
            for (int i = q * 32; i < q * 32 + 32; i++) s += W2[i * 128 + j] * u2[i];
            red[t] = s;
        }
        __syncthreads();
        if (t < 128) {
            float vj = (red[t] + red[128 + t]) + (red[256 + t] + red[384 + t]);
            v[t] = vj; sq[t] = vj * vj;
        }
        __syncthreads();
        for (int s2 = 64; s2 > 0; s2 >>= 1) {
            if (t < s2) sq[t] += sq[t + s2];
            __syncthreads();
        }
        if (t < 128) v[t] = v[t] / (sqrtf(sq[0]) + 1e-12f);
        __syncthreads();
        {
            int r = t >> 2, h = t & 3;
            const float4* wr = (const float4*)(W2 + r * 128 + h * 32);
            const float4* vv = (const float4*)v + h * 8;
            float s = 0.f;
#pragma unroll
            for (int k = 0; k < 8; k++) {
                float4 a = wr[k]; float4 b = vv[k];
                s += a.x * b.x + a.y * b.y + a.z * b.z + a.w * b.w;
            }
            red[t] = s;
        }
        __syncthreads();
        if (t < 128) {
            float tr = (red[4 * t] + red[4 * t + 1]) + (red[4 * t + 2] + red[4 * t + 3]);
            sq[t] = tr * tr;
        }
        __syncthreads();
        for (int s2 = 64; s2 > 0; s2 >>= 1) {
            if (t < s2) sq[t] += sq[t + s2];
            __syncthreads();
        }
        if (t == 0) { float nt2 = sq[0]; sinv[1] = (sqrtf(nt2) + 1e-12f) / nt2; }
    }
}

// ================= K2: aggregate + gemm1 fused =================
// One 1024-thread block (16 waves) per bucket of 128 nodes.
// Gather: each wave owns 8 nodes (4 node-pairs), same 8-chain ILP as the
// proven round-1 structure -> 2x resident waves/CU.
// MFMA/epilogue: waves 0-7 (t<512), proven 16-node/wave mapping.
__global__ __launch_bounds__(1024, 8) void k2_agg_gemm1(
        const unsigned* __restrict__ pairs,
        const int* __restrict__ gcount,
        const unsigned* __restrict__ xbf2,
        const short* __restrict__ w1bf,
        const float* __restrict__ b1,
        const float* __restrict__ sinv,
        char* __restrict__ outbase,          // d_out as bytes
        float* __restrict__ bnacc) {
    __shared__ short u[16384];              // 32 KB multi-use
    __shared__ unsigned short sorted[CAP];  // 5.5 KB
    __shared__ int hist[128];
    __shared__ int offs[128];
    __shared__ int cur[128];
    __shared__ float red1[1024], red2[1024];
    int t = threadIdx.x;
    int b = blockIdx.x;
    int cnt = gcount[b];

    // ---- CSR build (ep staged in u's first 11 KB) ----
    unsigned* ep = (unsigned*)u;
    {
        const uint4* gp4 = (const uint4*)(pairs + (size_t)b * CAP);
        int cnt4 = (cnt + 3) >> 2;
        for (int j = t; j < cnt4; j += 1024) ((uint4*)ep)[j] = gp4[j];
    }
    if (t < 128) hist[t] = 0;
    __syncthreads();
    for (int j = t; j < cnt; j += 1024) atomicAdd(&hist[ep[j] & 127u], 1);
    __syncthreads();
    // single-wave pair scan of hist[128] (2 elems/lane, wave 0)
    if (t < 64) {
        int e0 = hist[2 * t], e1 = hist[2 * t + 1];
        int s = e0 + e1;
#pragma unroll
        for (int o = 1; o < 64; o <<= 1) {
            int v = __shfl_up(s, o);
            if (t >= o) s += v;
        }
        int excl = s - (e0 + e1);          // exclusive prefix of the pair
        hist[2 * t]     = excl + e0;       // inclusive at 2t
        hist[2 * t + 1] = excl + e0 + e1;  // inclusive at 2t+1
        offs[2 * t]     = excl;
        cur[2 * t]      = excl;
        offs[2 * t + 1] = excl + e0;
        cur[2 * t + 1]  = excl + e0;
    }
    __syncthreads();
    for (int j = t; j < cnt; j += 1024) {
        unsigned v = ep[j];
        int p = atomicAdd(&cur[v & 127u], 1);
        sorted[p] = (unsigned short)(v >> 7);
    }
    __syncthreads();   // ep dead from here; u free

    // ---- stage W1 early so its loads overlap the gather ----
    {
        const bf8* wsrc = (const bf8*)w1bf;
        int idx = t;                         // 1024 bf8, one per thread
        int row = idx >> 3, c = idx & 7;
        int cs = c ^ (row & 7);
        *(bf8*)&u[8192 + row * 64 + cs * 8] = wsrc[idx];
    }

    // ---- 2-node interleaved register gather, direct LDS h-row writes ----
    int w = t >> 6;           // wave 0..15
    int lane = t & 63;
    int h = lane >> 5;        // edge parity
    int l = lane & 31;        // feature pair (2l, 2l+1)

#pragma unroll
    for (int np = 0; np < 4; np++) {
        int nA = w * 8 + np * 2;
        int nB = nA + 1;
        // self rows: issue first, consumed last (in flight across the gather)
        unsigned xsA = xbf2[(size_t)(b * 128 + nA) * 32 + l];
        unsigned xsB = xbf2[(size_t)(b * 128 + nB) * 32 + l];
        int begA = offs[nA], endA = hist[nA];
        int begB = offs[nB], endB = hist[nB];
        float aA0 = 0.f, aA1 = 0.f, bA0 = 0.f, bA1 = 0.f;
        float cA0 = 0.f, cA1 = 0.f, dA0 = 0.f, dA1 = 0.f;
        float aB0 = 0.f, aB1 = 0.f, bB0 = 0.f, bB1 = 0.f;
        float cB0 = 0.f, cB1 = 0.f, dB0 = 0.f, dB1 = 0.f;
        int jA = begA + h, jB = begB + h;
        // fused main: 8 loads in flight (common case, uniform condition)
        while (jA + 6 < endA && jB + 6 < endB) {
            int sA0 = sorted[jA],     sA1 = sorted[jA + 2];
            int sA2 = sorted[jA + 4], sA3 = sorted[jA + 6];
            int sB0 = sorted[jB],     sB1 = sorted[jB + 2];
            int sB2 = sorted[jB + 4], sB3 = sorted[jB + 6];
            unsigned vA0 = xbf2[(size_t)sA0 * 32 + l];
            unsigned vA1 = xbf2[(size_t)sA1 * 32 + l];
            unsigned vA2 = xbf2[(size_t)sA2 * 32 + l];
            unsigned vA3 = xbf2[(size_t)sA3 * 32 + l];
            unsigned vB0 = xbf2[(size_t)sB0 * 32 + l];
            unsigned vB1 = xbf2[(size_t)sB1 * 32 + l];
            unsigned vB2 = xbf2[(size_t)sB2 * 32 + l];
            unsigned vB3 = xbf2[(size_t)sB3 * 32 + l];
            aA0 += bf2f((unsigned short)vA0); aA1 += bf2f((unsigned short)(vA0 >> 16));
            bA0 += bf2f((unsigned short)vA1); bA1 += bf2f((unsigned short)(vA1 >> 16));
            cA0 += bf2f((unsigned short)vA2); cA1 += bf2f((unsigned short)(vA2 >> 16));
            dA0 += bf2f((unsigned short)vA3); dA1 += bf2f((unsigned short)(vA3 >> 16));
            aB0 += bf2f((unsigned short)vB0); aB1 += bf2f((unsigned short)(vB0 >> 16));
            bB0 += bf2f((unsigned short)vB1); bB1 += bf2f((unsigned short)(vB1 >> 16));
            cB0 += bf2f((unsigned short)vB2); cB1 += bf2f((unsigned short)(vB2 >> 16));
            dB0 += bf2f((unsigned short)vB3); dB1 += bf2f((unsigned short)(vB3 >> 16));
            jA += 8; jB += 8;
        }
        while (jA + 6 < endA) {
            int s0 = sorted[jA],     s1 = sorted[jA + 2];
            int s2 = sorted[jA + 4], s3 = sorted[jA + 6];
            unsigned v0 = xbf2[(size_t)s0 * 32 + l];
            unsigned v1 = xbf2[(size_t)s1 * 32 + l];
            unsigned v2 = xbf2[(size_t)s2 * 32 + l];
            unsigned v3 = xbf2[(size_t)s3 * 32 + l];
            aA0 += bf2f((unsigned short)v0); aA1 += bf2f((unsigned short)(v0 >> 16));
            bA0 += bf2f((unsigned short)v1); bA1 += bf2f((unsigned short)(v1 >> 16));
            cA0 += bf2f((unsigned short)v2); cA1 += bf2f((unsigned short)(v2 >> 16));
            dA0 += bf2f((unsigned short)v3); dA1 += bf2f((unsigned short)(v3 >> 16));
            jA += 8;
        }
        while (jB + 6 < endB) {
            int s0 = sorted[jB],     s1 = sorted[jB + 2];
            int s2 = sorted[jB + 4], s3 = sorted[jB + 6];
            unsigned v0 = xbf2[(size_t)s0 * 32 + l];
            unsigned v1 = xbf2[(size_t)s1 * 32 + l];
            unsigned v2 = xbf2[(size_t)s2 * 32 + l];
            unsigned v3 = xbf2[(size_t)s3 * 32 + l];
            aB0 += bf2f((unsigned short)v0); aB1 += bf2f((unsigned short)(v0 >> 16));
            bB0 += bf2f((unsigned short)v1); bB1 += bf2f((unsigned short)(v1 >> 16));
            cB0 += bf2f((unsigned short)v2); cB1 += bf2f((unsigned short)(v2 >> 16));
            dB0 += bf2f((unsigned short)v3); dB1 += bf2f((unsigned short)(v3 >> 16));
            jB += 8;
        }
        // predicated tails: provably <=3 loads each (end - j <= 6, stride 2)
        {
            bool pA0 = jA < endA, pA1 = jA + 2 < endA, pA2 = jA + 4 < endA;
            bool pB0 = jB < endB, pB1 = jB + 2 < endB, pB2 = jB + 4 < endB;
            int iA0 = pA0 ? jA : 0, iA1 = pA1 ? jA + 2 : 0, iA2 = pA2 ? jA + 4 : 0;
            int iB0 = pB0 ? jB : 0, iB1 = pB1 ? jB + 2 : 0, iB2 = pB2 ? jB + 4 : 0;
            int sA0 = sorted[iA0], sA1 = sorted[iA1], sA2 = sorted[iA2];
            int sB0 = sorted[iB0], sB1 = sorted[iB1], sB2 = sorted[iB2];
            unsigned vA0 = xbf2[(size_t)sA0 * 32 + l];
            unsigned vA1 = xbf2[(size_t)sA1 * 32 + l];
            unsigned vA2 = xbf2[(size_t)sA2 * 32 + l];
            unsigned vB0 = xbf2[(size_t)sB0 * 32 + l];
            unsigned vB1 = xbf2[(size_t)sB1 * 32 + l];
            unsigned vB2 = xbf2[(size_t)sB2 * 32 + l];
            aA0 += pA0 ? bf2f((unsigned short)vA0) : 0.f;
            aA1 += pA0 ? bf2f((unsigned short)(vA0 >> 16)) : 0.f;
            bA0 += pA1 ? bf2f((unsigned short)vA1) : 0.f;
            bA1 += pA1 ? bf2f((unsigned short)(vA1 >> 16)) : 0.f;
            cA0 += pA2 ? bf2f((unsigned short)vA2) : 0.f;
            cA1 += pA2 ? bf2f((unsigned short)(vA2 >> 16)) : 0.f;
            aB0 += pB0 ? bf2f((unsigned short)vB0) : 0.f;
            aB1 += pB0 ? bf2f((unsigned short)(vB0 >> 16)) : 0.f;
            bB0 += pB1 ? bf2f((unsigned short)vB1) : 0.f;
            bB1 += pB1 ? bf2f((unsigned short)(vB1 >> 16)) : 0.f;
            cB0 += pB2 ? bf2f((unsigned short)vB2) : 0.f;
            cB1 += pB2 ? bf2f((unsigned short)(vB2 >> 16)) : 0.f;
        }
        float sA0f = (aA0 + bA0) + (cA0 + dA0);
        float sA1f = (aA1 + bA1) + (cA1 + dA1);
        float sB0f = (aB0 + bB0) + (cB0 + dB0);
        float sB1f = (aB1 + bB1) + (cB1 + dB1);
        sA0f += __shfl_xor(sA0f, 32);
        sA1f += __shfl_xor(sA1f, 32);
        sB0f += __shfl_xor(sB0f, 32);
        sB1f += __shfl_xor(sB1f, 32);
        sA0f += bf2f((unsigned short)xsA);
        sA1f += bf2f((unsigned short)(xsA >> 16));
        sB0f += bf2f((unsigned short)xsB);
        sB1f += bf2f((unsigned short)(xsB >> 16));
        if (h == 0) {
            int c = l >> 2;
            int csA = c ^ (nA & 7);
            int csB = c ^ (nB & 7);
            *(unsigned*)&u[nA * 64 + csA * 8 + (l & 3) * 2] = pk2(sA0f, sA1f);
            *(unsigned*)&u[nB * 64 + csB * 8 + (l & 3) * 2] = pk2(sB0f, sB1f);
        }
    }
    __syncthreads();   // h tile + W1 tile ready

    // ---- MFMA: waves 0-7 (t<512), wave w handles nodes w*16..+15 ----
    int l15 = lane & 15, quad = lane >> 4;
    float s1 = sinv[0];
    f4 acc[8];
#pragma unroll
    for (int nt = 0; nt < 8; nt++) acc[nt] = (f4){0.f, 0.f, 0.f, 0.f};

    if (t < 512) {
#pragma unroll
        for (int ks = 0; ks < 2; ks++) {
            bf8 a, bfr[8];
            {
                int node = w * 16 + l15;
                int cs = (ks * 4 + quad) ^ (node & 7);
                a = *(const bf8*)&u[node * 64 + cs * 8];
            }
#pragma unroll
            for (int nt = 0; nt < 8; nt++) {
                int o = nt * 16 + l15;
                int cs = (ks * 4 + quad) ^ (o & 7);
                bfr[nt] = *(const bf8*)&u[8192 + o * 64 + cs * 8];
            }
#pragma unroll
            for (int nt = 0; nt < 8; nt++)
                acc[nt] = __builtin_amdgcn_mfma_f32_16x16x32_bf16(a, bfr[nt], acc[nt], 0, 0, 0);
        }

        // ---- epilogue: relu(s1*acc+b1), BN col sums ----
#pragma unroll
        for (int nt = 0; nt < 8; nt++) {
            float bb = b1[nt * 16 + l15];
            float s = 0.f, q = 0.f;
#pragma unroll
            for (int r = 0; r < 4; r++) {
                float v = fmaxf(fmaf(acc[nt][r], s1, bb), 0.f);
                acc[nt][r] = v;
                s += v; q += v * v;
            }
            s += __shfl_xor(s, 16); s += __shfl_xor(s, 32);
            q += __shfl_xor(q, 16); q += __shfl_xor(q, 32);
            if (quad == 0) {
                red1[w * 128 + nt * 16 + l15] = s;
                red2[w * 128 + nt * 16 + l15] = q;
            }
        }
    }
    __syncthreads();   // fragments consumed; reuse u as h1 tile (128x128 bf16)

    if (t < 512) {
#pragma unroll
        for (int nt = 0; nt < 8; nt++) {
            int col = nt * 16 + l15;
#pragma unroll
            for (int r = 0; r < 4; r++) {
                int row = w * 16 + quad * 4 + r;
                int cs = (col >> 3) ^ (row & 15);
                u[row * 128 + cs * 8 + (col & 7)] = f2bf(acc[nt][r]);
            }
        }
    }
    __syncthreads();

    // ---- h1 tile -> d_out slot b (first 32 KB of its 64 KB region) ----
    bf8* dst = (bf8*)(outbase + (size_t)b * 65536);
#pragma unroll
    for (int i = 0; i < 2; i++) {
        int idx = i * 1024 + t;             // 2048 bf8
        int row = idx >> 4, c = idx & 15;
        int cs = c ^ (row & 15);
        dst[idx] = *(const bf8*)&u[row * 128 + cs * 8];
    }
    // BN atomics
    if (t < 128) {
        float s = 0.f, q = 0.f;
#pragma unroll
        for (int g = 0; g < 8; g++) { s += red1[g * 128 + t]; q += red2[g * 128 + t]; }
        atomicAdd(&bnacc[t], s);
        atomicAdd(&bnacc[128 + t], q);
    }
}

// ================= K3: BN fold + gemm2 fused =================
// 512 blocks x 256 threads. Each block: fold W2 (redundant, cheap) into LDS
// bf16, stage its h1 tile from d_out slot, MFMA, overwrite slot with fp32 out.
__global__ __launch_bounds__(256) void k3_fold_gemm2(
        const float* __restrict__ bnacc, int N,
        const float* __restrict__ gamma,
        const float* __restrict__ beta,
        const float* __restrict__ W2,
        const float* __restrict__ b2,
        const float* __restrict__ sinv,
        char* __restrict__ outbase) {
    __shared__ short s5[32768];   // [0..16383]=h1 tile, [16384..]=w2s; 64 KB
    float* fs = (float*)s5;       // transient: a_s[0..127], c_s[128..255], b2f[256..383]
    int t = threadIdx.x;
    int b = blockIdx.x;

    if (t < 128) {
        float mean = bnacc[t] / (float)N;
        float var = bnacc[t + 128] / (float)N - mean * mean;
        float rstd = rsqrtf(var + BN_EPS);
        float a = rstd * gamma[t];
        fs[t] = a;
        fs[128 + t] = beta[t] - mean * a;
    }
    __syncthreads();

    // stage folded W2 (bf16, 16-chunk swizzle): thread -> row o=t>>1, 64 cols
    float s2 = sinv[1];
    {
        int o = t >> 1;
        int jbase = (t & 1) * 64;
        const float4* wr = (const float4*)(W2 + o * 128 + jbase);
#pragma unroll
        for (int k = 0; k < 8; k++) {
            int c = (jbase >> 3) + k;
            float4 a = wr[2 * k], bb = wr[2 * k + 1];
            int j0 = jbase + k * 8;
            bf8 v;
            v[0] = f2bf(a.x * s2 * fs[j0 + 0]);
            v[1] = f2bf(a.y * s2 * fs[j0 + 1]);
            v[2] = f2bf(a.z * s2 * fs[j0 + 2]);
            v[3] = f2bf(a.w * s2 * fs[j0 + 3]);
            v[4] = f2bf(bb.x * s2 * fs[j0 + 4]);
            v[5] = f2bf(bb.y * s2 * fs[j0 + 5]);
            v[6] = f2bf(bb.z * s2 * fs[j0 + 6]);
            v[7] = f2bf(bb.w * s2 * fs[j0 + 7]);
            int cs = c ^ (o & 15);
            *(bf8*)&s5[16384 + o * 128 + cs * 8] = v;
        }
    }
    // exact fp32 b2f (vectorized: 32 float4 loads, unrolled, s2 folded once)
    if (t < 128) {
        const float4* wr = (const float4*)(W2 + t * 128);
        float accb = 0.f;
#pragma unroll
        for (int k = 0; k < 32; k++) {
            float4 a = wr[k];
            accb += a.x * fs[128 + 4 * k + 0] + a.y * fs[128 + 4 * k + 1] +
                    a.z * fs[128 + 4 * k + 2] + a.w * fs[128 + 4 * k + 3];
        }
        fs[256 + t] = b2[t] + accb * s2;
    }
    __syncthreads();

    int w = t >> 6;
    int lane = t & 63;
    int l15 = lane & 15, quad = lane >> 4;
    float b2v[8];
#pragma unroll
    for (int nt = 0; nt < 8; nt++) b2v[nt] = fs[256 + nt * 16 + l15];
    __syncthreads();   // b2v read; fs region free for h1 tile

    // stage h1 tile from d_out slot b
    {
        const bf8* hsrc = (const bf8*)(outbase + (size_t)b * 65536);
#pragma unroll
        for (int i = 0; i < 8; i++) {
            int idx = i * 256 + t;          // 2048 bf8
            int row = idx >> 4, c = idx & 15;
            int cs = c ^ (row & 15);
            *(bf8*)&s5[row * 128 + cs * 8] = hsrc[idx];
        }
    }
    __syncthreads();

    f4 acc[2][8];
#pragma unroll
    for (int mt = 0; mt < 2; mt++)
#pragma unroll
        for (int nt = 0; nt < 8; nt++) acc[mt][nt] = (f4){0.f, 0.f, 0.f, 0.f};

#pragma unroll
    for (int ks = 0; ks < 4; ks++) {
        bf8 a[2], bfr[8];
#pragma unroll
        for (int mt = 0; mt < 2; mt++) {
            int node = w * 32 + mt * 16 + l15;
            int cs = (ks * 4 + quad) ^ (node & 15);
            a[mt] = *(const bf8*)&s5[node * 128 + cs * 8];
        }
#pragma unroll
        for (int nt = 0; nt < 8; nt++) {
            int o = nt * 16 + l15;
            int cs = (ks * 4 + quad) ^ (o & 15);
            bfr[nt] = *(const bf8*)&s5[16384 + o * 128 + cs * 8];
        }
#pragma unroll
        for (int mt = 0; mt < 2; mt++)
#pragma unroll
            for (int nt = 0; nt < 8; nt++)
                acc[mt][nt] = __builtin_amdgcn_mfma_f32_16x16x32_bf16(
                    a[mt], bfr[nt], acc[mt][nt], 0, 0, 0);
    }

    float* out = (float*)(outbase + (size_t)b * 65536);
#pragma unroll
    for (int mt = 0; mt < 2; mt++)
#pragma unroll
        for (int nt = 0; nt < 8; nt++)
#pragma unroll
            for (int r = 0; r < 4; r++) {
                int row = w * 32 + mt * 16 + quad * 4 + r;   // local node
                out[(size_t)row * 128 + nt * 16 + l15] = acc[mt][nt][r] + b2v[nt];
            }
}

extern "C" void kernel_launch(void* const* d_in, const int* in_sizes, int n_in,
                              void* d_out, int out_size, void* d_ws, size_t ws_size,
                              hipStream_t stream) {
    const float* x     = (const float*)d_in[0];
    const int*   ei    = (const int*)d_in[1];
    const float* W1    = (const float*)d_in[2];
    const float* b1    = (const float*)d_in[3];
    const float* u1    = (const float*)d_in[4];
    const float* gamma = (const float*)d_in[5];
    const float* beta  = (const float*)d_in[6];
    const float* W2    = (const float*)d_in[7];
    const float* b2    = (const float*)d_in[8];
    const float* u2    = (const float*)d_in[9];

    int N = in_sizes[0] / 64;     // 65536
    int E = in_sizes[1] / 2;      // 1048576

    char* ws = (char*)d_ws;
    size_t off = 0;
    unsigned* pairs = (unsigned*)(ws + off); off += (size_t)NB * CAP * 4;  // 5.77 MB
    unsigned short* xbf = (unsigned short*)(ws + off); off += (size_t)N * 64 * 2; // 8 MB
    int*   gcount  = (int*)(ws + off);   off += 512 * 4;
    float* bnacc   = (float*)(ws + off); off += 256 * 4;   // contiguous w/ gcount
    float* sinv    = (float*)(ws + off); off += 16 * 4;
    short* w1bf    = (short*)(ws + off); off += 128 * 64 * 2;

    // zero gcount(512 int) + bnacc(256 float) in one memset (contiguous)
    hipMemsetAsync(gcount, 0, 512 * 4 + 256 * 4, stream);
    // K1: binning + x/W1 casts + sigmas
    k1_bin<<<513, 512, 0, stream>>>(ei, E, gcount, pairs, x, (unsigned*)xbf,
                                    W1, w1bf, u1, W2, u2, sinv);
    // K2: aggregate + gemm1 -> h1 bf16 tiles into d_out slots + BN atomics
    k2_agg_gemm1<<<NB, 1024, 0, stream>>>(pairs, gcount, (const unsigned*)xbf,
                                          w1bf, b1, sinv, (char*)d_out, bnacc);
    // K3: BN fold + gemm2, in place on d_out
    k3_fold_gemm2<<<NB, 256, 0, stream>>>(bnacc, N, gamma, beta, W2, b2, sinv,
                                          (char*)d_out);
}